// Round 8
// baseline (630.766 us; speedup 1.0000x reference)
//
#include <hip/hip_runtime.h>
#include <math.h>

#define NTOK 768
#define CS   384
#define CZ   128
#define NH   12
#define INF_ 100000.0f
#define EPS_ 1e-8f

typedef unsigned int  uint32;
typedef unsigned short ushort16;

__device__ __forceinline__ uint32 bf16rn(float x) {
    uint32 u = __float_as_uint(x);
    return (u + 0x7fffu + ((u >> 16) & 1u)) >> 16;
}
__device__ __forceinline__ float bflo(uint32 u) { return __uint_as_float((u & 0xffffu) << 16); }
__device__ __forceinline__ float bfhi(uint32 u) { return __uint_as_float(u & 0xffff0000u); }

// ---------------------------------------------------------------------------
// K1a: tiled GEMM. RAW[col][tok] = sum_k s[tok][k] * Wcat[k][col]  (no bias).
// ---------------------------------------------------------------------------
__global__ __launch_bounds__(256) void k1a_gemm(
    const float* __restrict__ s,
    const float* __restrict__ wq, const float* __restrict__ wkv,
    const float* __restrict__ wqp, const float* __restrict__ wkvp,
    float* __restrict__ RAW)
{
    __shared__ float sA[32][72];   // [k][m]
    __shared__ float sB[32][72];   // [k][n]
    const int tid  = threadIdx.x;
    const int tok0 = blockIdx.x * 64;
    const int col0 = blockIdx.y * 64;

    const int m0 = (tid & 15) * 4;
    const int n0 = (tid >> 4) * 4;

    float4 acc[4];
    #pragma unroll
    for (int nn = 0; nn < 4; nn++) acc[nn] = make_float4(0.f, 0.f, 0.f, 0.f);

    const int lam = tid >> 2, lak = (tid & 3) * 8;
    const int lbk = tid >> 3, lbc = (tid & 7) * 8;
    const int gcol = col0 + lbc;
    const float* wsrc; int wwidth, woff;
    if (gcol < 192)      { wsrc = wq;   wwidth = 192; woff = gcol; }
    else if (gcol < 576) { wsrc = wkv;  wwidth = 384; woff = gcol - 192; }
    else if (gcol < 720) { wsrc = wqp;  wwidth = 144; woff = gcol - 576; }
    else                 { wsrc = wkvp; wwidth = 432; woff = gcol - 720; }

    for (int kb = 0; kb < CS; kb += 32) {
        const float4 a0 = *(const float4*)&s[(tok0 + lam) * CS + kb + lak];
        const float4 a1 = *(const float4*)&s[(tok0 + lam) * CS + kb + lak + 4];
        const float4 b0 = *(const float4*)&wsrc[(size_t)(kb + lbk) * wwidth + woff];
        const float4 b1 = *(const float4*)&wsrc[(size_t)(kb + lbk) * wwidth + woff + 4];
        __syncthreads();
        sA[lak + 0][lam] = a0.x; sA[lak + 1][lam] = a0.y;
        sA[lak + 2][lam] = a0.z; sA[lak + 3][lam] = a0.w;
        sA[lak + 4][lam] = a1.x; sA[lak + 5][lam] = a1.y;
        sA[lak + 6][lam] = a1.z; sA[lak + 7][lam] = a1.w;
        *(float4*)&sB[lbk][lbc]     = b0;
        *(float4*)&sB[lbk][lbc + 4] = b1;
        __syncthreads();
        #pragma unroll
        for (int k = 0; k < 32; k++) {
            const float4 av = *(const float4*)&sA[k][m0];
            const float4 bv = *(const float4*)&sB[k][n0];
            acc[0].x += av.x * bv.x; acc[0].y += av.y * bv.x; acc[0].z += av.z * bv.x; acc[0].w += av.w * bv.x;
            acc[1].x += av.x * bv.y; acc[1].y += av.y * bv.y; acc[1].z += av.z * bv.y; acc[1].w += av.w * bv.y;
            acc[2].x += av.x * bv.z; acc[2].y += av.y * bv.z; acc[2].z += av.z * bv.z; acc[2].w += av.w * bv.z;
            acc[3].x += av.x * bv.w; acc[3].y += av.y * bv.w; acc[3].z += av.z * bv.w; acc[3].w += av.w * bv.w;
        }
    }
    #pragma unroll
    for (int nn = 0; nn < 4; nn++)
        *(float4*)&RAW[(size_t)(col0 + n0 + nn) * NTOK + tok0 + m0] = acc[nn];
}

// ---------------------------------------------------------------------------
// K1b: bias + layout + rigid transform. 16 tokens/block, lane=token.
// ---------------------------------------------------------------------------
__global__ __launch_bounds__(256) void k1b_finish(
    const float* __restrict__ RAW,
    const float* __restrict__ rot, const float* __restrict__ trans,
    const float* __restrict__ bq, const float* __restrict__ bkv,
    const float* __restrict__ bqp, const float* __restrict__ bkvp,
    float* __restrict__ Q, float* __restrict__ KT, float* __restrict__ VT,
    float* __restrict__ QP, float* __restrict__ KPT, float* __restrict__ VPT)
{
    const int tid = threadIdx.x;
    const int t  = blockIdx.x * 16 + (tid & 15);
    const int wk = tid >> 4;                      // 16 walkers

    float R[9], T3[3];
    #pragma unroll
    for (int x = 0; x < 9; x++) R[x] = rot[t * 9 + x];
    #pragma unroll
    for (int x = 0; x < 3; x++) T3[x] = trans[t * 3 + x];

    for (int col = wk; col < 192; col += 16)
        Q[t * 192 + col] = RAW[(size_t)col * NTOK + t] + bq[col];

    for (int idx = wk; idx < 192; idx += 16) {
        const int h = idx >> 4, c = idx & 15;
        KT[idx * NTOK + t] = RAW[(size_t)(192 + h * 32 + c)      * NTOK + t] + bkv[h * 32 + c];
        VT[idx * NTOK + t] = RAW[(size_t)(192 + h * 32 + 16 + c) * NTOK + t] + bkv[h * 32 + 16 + c];
    }

    for (int pidx = wk; pidx < 48; pidx += 16) {
        const float r0 = RAW[(size_t)(576 + 0 * 48 + pidx) * NTOK + t] + bqp[0 * 48 + pidx];
        const float r1 = RAW[(size_t)(576 + 1 * 48 + pidx) * NTOK + t] + bqp[1 * 48 + pidx];
        const float r2 = RAW[(size_t)(576 + 2 * 48 + pidx) * NTOK + t] + bqp[2 * 48 + pidx];
        #pragma unroll
        for (int x = 0; x < 3; x++)
            QP[t * 144 + pidx * 3 + x] = R[x*3+0]*r0 + R[x*3+1]*r1 + R[x*3+2]*r2 + T3[x];
    }

    for (int pidx = wk; pidx < 144; pidx += 16) {
        const float r0 = RAW[(size_t)(720 + 0 * 144 + pidx) * NTOK + t] + bkvp[0 * 144 + pidx];
        const float r1 = RAW[(size_t)(720 + 1 * 144 + pidx) * NTOK + t] + bkvp[1 * 144 + pidx];
        const float r2 = RAW[(size_t)(720 + 2 * 144 + pidx) * NTOK + t] + bkvp[2 * 144 + pidx];
        const int h = pidx / 12, pp = pidx % 12;
        #pragma unroll
        for (int x = 0; x < 3; x++) {
            const float v = R[x*3+0]*r0 + R[x*3+1]*r1 + R[x*3+2]*r2 + T3[x];
            if (pp < 4) KPT[((h * 4 + pp)  * 3 + x) * NTOK + t] = v;
            else        VPT[((h * 8 + pp - 4) * 3 + x) * NTOK + t] = v;
        }
    }
}

// ---------------------------------------------------------------------------
// K2: z projections, streaming. BBT[i][h][j] f32; PZT[i][j][c] bf16 (packed).
// NO min-occupancy bound (round-5 spill lesson).
// ---------------------------------------------------------------------------
__global__ __launch_bounds__(256) void k2_zproj(
    const float* __restrict__ z, const float* __restrict__ wb, const float* __restrict__ bb,
    const float* __restrict__ wdz, const float* __restrict__ bdz,
    float* __restrict__ BBT, ushort16* __restrict__ PZT)
{
    __shared__ float wL[CZ * 44];     // [k][44]: o<12 -> wb, else wdz
    __shared__ float biasL[44];
    const int tid = threadIdx.x;
    for (int idx = tid; idx < CZ * 44; idx += 256) {
        const int k = idx / 44, o = idx % 44;
        wL[idx] = (o < 12) ? wb[k * 12 + o] : wdz[k * 32 + (o - 12)];
    }
    if (tid < 44) biasL[tid] = (tid < 12) ? bb[tid] : bdz[tid - 12];
    __syncthreads();

    const int i = blockIdx.y;
    const int j = blockIdx.x * 256 + tid;
    const float4* zrow = (const float4*)(z + ((size_t)i * NTOK + j) * CZ);

    float acc[44];
    #pragma unroll
    for (int o = 0; o < 44; o++) acc[o] = biasL[o];

    #pragma unroll 4
    for (int k4 = 0; k4 < CZ / 4; k4++) {
        const float4 zv = zrow[k4];
        const float* w0 = &wL[(k4 * 4) * 44];
        #pragma unroll
        for (int o = 0; o < 44; o++)
            acc[o] += zv.x * w0[o] + zv.y * w0[o + 44] + zv.z * w0[o + 88] + zv.w * w0[o + 132];
    }

    #pragma unroll
    for (int h = 0; h < 12; h++) BBT[((size_t)i * 12 + h) * NTOK + j] = acc[h];

    uint32 pk[16];
    #pragma unroll
    for (int c2 = 0; c2 < 16; c2++)
        pk[c2] = bf16rn(acc[12 + 2 * c2]) | (bf16rn(acc[12 + 2 * c2 + 1]) << 16);
    uint4* dst = (uint4*)(PZT + ((size_t)i * NTOK + j) * 32);   // 64B/thread, coalesced
    dst[0] = make_uint4(pk[0],  pk[1],  pk[2],  pk[3]);
    dst[1] = make_uint4(pk[4],  pk[5],  pk[6],  pk[7]);
    dst[2] = make_uint4(pk[8],  pk[9],  pk[10], pk[11]);
    dst[3] = make_uint4(pk[12], pk[13], pk[14], pk[15]);
}

// ---------------------------------------------------------------------------
// K3: attention per row i. Phase-4 j-loops unrolled x4 with independent
// accumulator chains (round 7: single-acc dependent chain = latency-bound,
// VALUBusy 30%, 281 us).
// ---------------------------------------------------------------------------
__global__ __launch_bounds__(768) void k3_attn(
    const float* __restrict__ KT, const float* __restrict__ VT,
    const float* __restrict__ KPT, const float* __restrict__ VPT,
    const float* __restrict__ Q, const float* __restrict__ QP,
    const float* __restrict__ BBT, const ushort16* __restrict__ PZT,
    const float* __restrict__ mask, const float* __restrict__ head_weights,
    float* __restrict__ O, float* __restrict__ OPT, float* __restrict__ OPAIR)
{
    __shared__ float LB[NH][NTOK];      // logits -> probs in place
    __shared__ float qrow[192], qprow[144], hwL[NH];
    const int i = blockIdx.x, tid = threadIdx.x;

    if (tid < 192) qrow[tid] = Q[i * 192 + tid];
    else if (tid >= 256 && tid < 400) qprow[tid - 256] = QP[i * 144 + (tid - 256)];
    else if (tid >= 448 && tid < 460)
        hwL[tid - 448] = logf(1.0f + expf(head_weights[tid - 448])) * 0.13608276348795434f; // sqrt(1/54)
    __syncthreads();

    const float qk_scale = 0.14433756729740643f;   // sqrt(1/48)
    const float b_scale  = 0.5773502691896258f;    // sqrt(1/3)
    const int j = tid;
    const float mterm = INF_ * (mask[i] * mask[j] - 1.0f);
    #pragma unroll 1
    for (int h = 0; h < NH; h++) {
        float qk = 0.0f;
        #pragma unroll
        for (int c = 0; c < 16; c++)
            qk += qrow[h * 16 + c] * KT[(h * 16 + c) * NTOK + j];
        float pt = 0.0f;
        #pragma unroll
        for (int d = 0; d < 12; d++) {
            const float dv = qprow[h * 12 + d] - KPT[(h * 12 + d) * NTOK + j];
            pt += dv * dv;
        }
        LB[h][j] = qk * qk_scale + b_scale * BBT[((size_t)i * 12 + h) * NTOK + j]
                 - 0.5f * hwL[h] * pt + mterm;
    }
    __syncthreads();

    // softmax: wave w handles head w (12 waves exactly)
    {
        const int h = tid >> 6, lane = tid & 63;
        float m = -3.0e38f;
        for (int jj = lane; jj < NTOK; jj += 64) m = fmaxf(m, LB[h][jj]);
        #pragma unroll
        for (int off = 32; off >= 1; off >>= 1) m = fmaxf(m, __shfl_xor(m, off));
        float ssum = 0.0f;
        for (int jj = lane; jj < NTOK; jj += 64) {
            const float e = __expf(LB[h][jj] - m);
            LB[h][jj] = e;
            ssum += e;
        }
        #pragma unroll
        for (int off = 32; off >= 1; off >>= 1) ssum += __shfl_xor(ssum, off);
        const float inv = 1.0f / ssum;
        for (int jj = lane; jj < NTOK; jj += 64) LB[h][jj] *= inv;
    }
    __syncthreads();

    // weighted sums: per head 16 (o) + 24 (o_pt) + 16 (o_pair bf16x2) = 56 items
    if (tid < 672) {
        const int h = tid / 56, r = tid % 56;
        if (r < 40) {
            const float4* s4 = (r < 16) ? (const float4*)&VT[(h * 16 + r) * NTOK]
                                        : (const float4*)&VPT[(h * 24 + (r - 16)) * NTOK];
            const float4* a4 = (const float4*)&LB[h][0];
            float c0 = 0.f, c1 = 0.f, c2 = 0.f, c3 = 0.f;   // 4 independent chains
            for (int j4 = 0; j4 < NTOK / 4; j4 += 4) {
                const float4 a0 = a4[j4+0], v0 = s4[j4+0];
                const float4 a1 = a4[j4+1], v1 = s4[j4+1];
                const float4 a2 = a4[j4+2], v2 = s4[j4+2];
                const float4 a3 = a4[j4+3], v3 = s4[j4+3];
                c0 += a0.x*v0.x + a0.y*v0.y + a0.z*v0.z + a0.w*v0.w;
                c1 += a1.x*v1.x + a1.y*v1.y + a1.z*v1.z + a1.w*v1.w;
                c2 += a2.x*v2.x + a2.y*v2.y + a2.z*v2.z + a2.w*v2.w;
                c3 += a3.x*v3.x + a3.y*v3.y + a3.z*v3.z + a3.w*v3.w;
            }
            const float acc = (c0 + c1) + (c2 + c3);
            if (r < 16) O[i * 192 + h * 16 + r] = acc;
            else        OPT[i * 288 + h * 24 + (r - 16)] = acc;
        } else {
            const int c2i = r - 40;
            const uint32* pzr = (const uint32*)(PZT + (size_t)i * NTOK * 32);
            float s0 = 0.f, s1 = 0.f, s2 = 0.f, s3 = 0.f;   // lo accs
            float t0 = 0.f, t1 = 0.f, t2 = 0.f, t3 = 0.f;   // hi accs
            for (int jj = 0; jj < NTOK; jj += 4) {
                const uint32 u0 = pzr[(jj+0) * 16 + c2i];
                const uint32 u1 = pzr[(jj+1) * 16 + c2i];
                const uint32 u2 = pzr[(jj+2) * 16 + c2i];
                const uint32 u3 = pzr[(jj+3) * 16 + c2i];
                const float p0 = LB[h][jj+0], p1 = LB[h][jj+1];
                const float p2 = LB[h][jj+2], p3 = LB[h][jj+3];
                s0 += p0 * bflo(u0); t0 += p0 * bfhi(u0);
                s1 += p1 * bflo(u1); t1 += p1 * bfhi(u1);
                s2 += p2 * bflo(u2); t2 += p2 * bfhi(u2);
                s3 += p3 * bflo(u3); t3 += p3 * bfhi(u3);
            }
            OPAIR[i * 384 + h * 32 + 2 * c2i]     = (s0 + s1) + (s2 + s3);
            OPAIR[i * 384 + h * 32 + 2 * c2i + 1] = (t0 + t1) + (t2 + t3);
        }
    }
}

// ---------------------------------------------------------------------------
// K4: inverse rotation + norms + concat + final linear (8 tokens/block)
// ---------------------------------------------------------------------------
#define K4T 8
__global__ __launch_bounds__(256) void k4_out(
    const float* __restrict__ O, const float* __restrict__ OPT, const float* __restrict__ OPAIR,
    const float* __restrict__ rot, const float* __restrict__ trans,
    const float* __restrict__ wout, const float* __restrict__ bout,
    float* __restrict__ out)
{
    __shared__ float f[K4T][960];
    const int n0 = blockIdx.x * K4T, tid = threadIdx.x;

    for (int idx = tid; idx < K4T * 192; idx += 256) {
        const int t = idx / 192, k = idx % 192;
        f[t][k] = O[(n0 + t) * 192 + k];
    }
    for (int idx = tid; idx < K4T * 384; idx += 256) {
        const int t = idx / 384, k = idx % 384;
        f[t][576 + k] = OPAIR[(n0 + t) * 384 + k];
    }
    for (int idx = tid; idx < K4T * 96; idx += 256) {
        const int t = idx / 96, hp = idx % 96;
        const int n = n0 + t;
        const float vx = OPT[n * 288 + hp * 3 + 0] - trans[n * 3 + 0];
        const float vy = OPT[n * 288 + hp * 3 + 1] - trans[n * 3 + 1];
        const float vz = OPT[n * 288 + hp * 3 + 2] - trans[n * 3 + 2];
        const float o0 = rot[n*9+0]*vx + rot[n*9+3]*vy + rot[n*9+6]*vz;
        const float o1 = rot[n*9+1]*vx + rot[n*9+4]*vy + rot[n*9+7]*vz;
        const float o2 = rot[n*9+2]*vx + rot[n*9+5]*vy + rot[n*9+8]*vz;
        f[t][192 + hp] = o0;
        f[t][288 + hp] = o1;
        f[t][384 + hp] = o2;
        f[t][480 + hp] = sqrtf(o0*o0 + o1*o1 + o2*o2 + EPS_);
    }
    __syncthreads();

    for (int o = tid; o < 384; o += 256) {
        float acc[K4T];
        #pragma unroll
        for (int t = 0; t < K4T; t++) acc[t] = bout[o];
        for (int k = 0; k < 960; k++) {
            const float wv = wout[k * 384 + o];
            #pragma unroll
            for (int t = 0; t < K4T; t++) acc[t] += f[t][k] * wv;
        }
        #pragma unroll
        for (int t = 0; t < K4T; t++) out[(n0 + t) * 384 + o] = acc[t];
    }
}

// ---------------------------------------------------------------------------
extern "C" void kernel_launch(void* const* d_in, const int* in_sizes, int n_in,
                              void* d_out, int out_size, void* d_ws, size_t ws_size,
                              hipStream_t stream) {
    (void)in_sizes; (void)n_in; (void)out_size; (void)ws_size;
    const float* s     = (const float*)d_in[0];
    const float* z     = (const float*)d_in[1];
    const float* rot   = (const float*)d_in[2];
    const float* trans = (const float*)d_in[3];
    const float* mask  = (const float*)d_in[4];
    const float* wq    = (const float*)d_in[5];
    const float* bq    = (const float*)d_in[6];
    const float* wkv   = (const float*)d_in[7];
    const float* bkv   = (const float*)d_in[8];
    const float* wqp   = (const float*)d_in[9];
    const float* bqp   = (const float*)d_in[10];
    const float* wkvp  = (const float*)d_in[11];
    const float* bkvp  = (const float*)d_in[12];
    const float* wb    = (const float*)d_in[13];
    const float* bb    = (const float*)d_in[14];
    const float* wdz   = (const float*)d_in[15];
    const float* bdz   = (const float*)d_in[16];
    const float* hwts  = (const float*)d_in[17];
    const float* wout  = (const float*)d_in[18];
    const float* bout  = (const float*)d_in[19];
    float* out = (float*)d_out;

    float* ws = (float*)d_ws;
    float* Q     = ws;                       // 147456
    float* KT    = Q     + 147456;           // 147456
    float* VT    = KT    + 147456;           // 147456
    float* QP    = VT    + 147456;           // 110592
    float* KPT   = QP    + 110592;           // 110592
    float* VPT   = KPT   + 110592;           // 221184
    float* O     = VPT   + 221184;           // 147456
    float* OPT   = O     + 147456;           // 221184
    float* OPAIR = OPT   + 221184;           // 294912
    float* BBT   = OPAIR + 294912;           // 7,077,888 floats (28.3 MB)
    ushort16* PZT = (ushort16*)(BBT + 7077888); // 768*768*32 bf16 (37.7 MB)
    float* RAW = BBT;   // aliases BBT: dead before k2 runs

    hipLaunchKernelGGL(k1a_gemm, dim3(NTOK / 64, 1152 / 64), dim3(256), 0, stream,
                       s, wq, wkv, wqp, wkvp, RAW);
    hipLaunchKernelGGL(k1b_finish, dim3(NTOK / 16), dim3(256), 0, stream,
                       RAW, rot, trans, bq, bkv, bqp, bkvp,
                       Q, KT, VT, QP, KPT, VPT);
    hipLaunchKernelGGL(k2_zproj, dim3(3, NTOK), dim3(256), 0, stream,
                       z, wb, bb, wdz, bdz, BBT, PZT);
    hipLaunchKernelGGL(k3_attn, dim3(NTOK), dim3(768), 0, stream,
                       KT, VT, KPT, VPT, Q, QP, BBT, PZT, mask, hwts,
                       O, OPT, OPAIR);
    hipLaunchKernelGGL(k4_out, dim3(NTOK / K4T), dim3(256), 0, stream,
                       O, OPT, OPAIR, rot, trans, wout, bout, out);
}

// Round 9
// 501.784 us; speedup vs baseline: 1.2570x; 1.2570x over previous
//
#include <hip/hip_runtime.h>
#include <math.h>

#define NTOK 768
#define CS   384
#define CZ   128
#define NH   12
#define INF_ 100000.0f
#define EPS_ 1e-8f

typedef unsigned int  uint32;

__device__ __forceinline__ uint32 bf16rn(float x) {
    uint32 u = __float_as_uint(x);
    return (u + 0x7fffu + ((u >> 16) & 1u)) >> 16;
}
__device__ __forceinline__ float bflo(uint32 u) { return __uint_as_float((u & 0xffffu) << 16); }
__device__ __forceinline__ float bfhi(uint32 u) { return __uint_as_float(u & 0xffff0000u); }

// ---------------------------------------------------------------------------
// K1a: tiled GEMM. RAW[col][tok] = sum_k s[tok][k] * Wcat[k][col]  (no bias).
// ---------------------------------------------------------------------------
__global__ __launch_bounds__(256) void k1a_gemm(
    const float* __restrict__ s,
    const float* __restrict__ wq, const float* __restrict__ wkv,
    const float* __restrict__ wqp, const float* __restrict__ wkvp,
    float* __restrict__ RAW)
{
    __shared__ float sA[32][72];   // [k][m]
    __shared__ float sB[32][72];   // [k][n]
    const int tid  = threadIdx.x;
    const int tok0 = blockIdx.x * 64;
    const int col0 = blockIdx.y * 64;

    const int m0 = (tid & 15) * 4;
    const int n0 = (tid >> 4) * 4;

    float4 acc[4];
    #pragma unroll
    for (int nn = 0; nn < 4; nn++) acc[nn] = make_float4(0.f, 0.f, 0.f, 0.f);

    const int lam = tid >> 2, lak = (tid & 3) * 8;
    const int lbk = tid >> 3, lbc = (tid & 7) * 8;
    const int gcol = col0 + lbc;
    const float* wsrc; int wwidth, woff;
    if (gcol < 192)      { wsrc = wq;   wwidth = 192; woff = gcol; }
    else if (gcol < 576) { wsrc = wkv;  wwidth = 384; woff = gcol - 192; }
    else if (gcol < 720) { wsrc = wqp;  wwidth = 144; woff = gcol - 576; }
    else                 { wsrc = wkvp; wwidth = 432; woff = gcol - 720; }

    for (int kb = 0; kb < CS; kb += 32) {
        const float4 a0 = *(const float4*)&s[(tok0 + lam) * CS + kb + lak];
        const float4 a1 = *(const float4*)&s[(tok0 + lam) * CS + kb + lak + 4];
        const float4 b0 = *(const float4*)&wsrc[(size_t)(kb + lbk) * wwidth + woff];
        const float4 b1 = *(const float4*)&wsrc[(size_t)(kb + lbk) * wwidth + woff + 4];
        __syncthreads();
        sA[lak + 0][lam] = a0.x; sA[lak + 1][lam] = a0.y;
        sA[lak + 2][lam] = a0.z; sA[lak + 3][lam] = a0.w;
        sA[lak + 4][lam] = a1.x; sA[lak + 5][lam] = a1.y;
        sA[lak + 6][lam] = a1.z; sA[lak + 7][lam] = a1.w;
        *(float4*)&sB[lbk][lbc]     = b0;
        *(float4*)&sB[lbk][lbc + 4] = b1;
        __syncthreads();
        #pragma unroll
        for (int k = 0; k < 32; k++) {
            const float4 av = *(const float4*)&sA[k][m0];
            const float4 bv = *(const float4*)&sB[k][n0];
            acc[0].x += av.x * bv.x; acc[0].y += av.y * bv.x; acc[0].z += av.z * bv.x; acc[0].w += av.w * bv.x;
            acc[1].x += av.x * bv.y; acc[1].y += av.y * bv.y; acc[1].z += av.z * bv.y; acc[1].w += av.w * bv.y;
            acc[2].x += av.x * bv.z; acc[2].y += av.y * bv.z; acc[2].z += av.z * bv.z; acc[2].w += av.w * bv.z;
            acc[3].x += av.x * bv.w; acc[3].y += av.y * bv.w; acc[3].z += av.z * bv.w; acc[3].w += av.w * bv.w;
        }
    }
    #pragma unroll
    for (int nn = 0; nn < 4; nn++)
        *(float4*)&RAW[(size_t)(col0 + n0 + nn) * NTOK + tok0 + m0] = acc[nn];
}

// ---------------------------------------------------------------------------
// K1b: bias + layout + rigid transform. 16 tokens/block, lane=token.
// ---------------------------------------------------------------------------
__global__ __launch_bounds__(256) void k1b_finish(
    const float* __restrict__ RAW,
    const float* __restrict__ rot, const float* __restrict__ trans,
    const float* __restrict__ bq, const float* __restrict__ bkv,
    const float* __restrict__ bqp, const float* __restrict__ bkvp,
    float* __restrict__ Q, float* __restrict__ KT, float* __restrict__ VT,
    float* __restrict__ QP, float* __restrict__ KPT, float* __restrict__ VPT)
{
    const int tid = threadIdx.x;
    const int t  = blockIdx.x * 16 + (tid & 15);
    const int wk = tid >> 4;                      // 16 walkers

    float R[9], T3[3];
    #pragma unroll
    for (int x = 0; x < 9; x++) R[x] = rot[t * 9 + x];
    #pragma unroll
    for (int x = 0; x < 3; x++) T3[x] = trans[t * 3 + x];

    for (int col = wk; col < 192; col += 16)
        Q[t * 192 + col] = RAW[(size_t)col * NTOK + t] + bq[col];

    for (int idx = wk; idx < 192; idx += 16) {
        const int h = idx >> 4, c = idx & 15;
        KT[idx * NTOK + t] = RAW[(size_t)(192 + h * 32 + c)      * NTOK + t] + bkv[h * 32 + c];
        VT[idx * NTOK + t] = RAW[(size_t)(192 + h * 32 + 16 + c) * NTOK + t] + bkv[h * 32 + 16 + c];
    }

    for (int pidx = wk; pidx < 48; pidx += 16) {
        const float r0 = RAW[(size_t)(576 + 0 * 48 + pidx) * NTOK + t] + bqp[0 * 48 + pidx];
        const float r1 = RAW[(size_t)(576 + 1 * 48 + pidx) * NTOK + t] + bqp[1 * 48 + pidx];
        const float r2 = RAW[(size_t)(576 + 2 * 48 + pidx) * NTOK + t] + bqp[2 * 48 + pidx];
        #pragma unroll
        for (int x = 0; x < 3; x++)
            QP[t * 144 + pidx * 3 + x] = R[x*3+0]*r0 + R[x*3+1]*r1 + R[x*3+2]*r2 + T3[x];
    }

    for (int pidx = wk; pidx < 144; pidx += 16) {
        const float r0 = RAW[(size_t)(720 + 0 * 144 + pidx) * NTOK + t] + bkvp[0 * 144 + pidx];
        const float r1 = RAW[(size_t)(720 + 1 * 144 + pidx) * NTOK + t] + bkvp[1 * 144 + pidx];
        const float r2 = RAW[(size_t)(720 + 2 * 144 + pidx) * NTOK + t] + bkvp[2 * 144 + pidx];
        const int h = pidx / 12, pp = pidx % 12;
        #pragma unroll
        for (int x = 0; x < 3; x++) {
            const float v = R[x*3+0]*r0 + R[x*3+1]*r1 + R[x*3+2]*r2 + T3[x];
            if (pp < 4) KPT[((h * 4 + pp)  * 3 + x) * NTOK + t] = v;
            else        VPT[((h * 8 + pp - 4) * 3 + x) * NTOK + t] = v;
        }
    }
}

// ---------------------------------------------------------------------------
// K2: z projections. BBT[i][h][j] f32; PZT32[i][c2][j] u32 (=2 bf16), so
// k3's o_pair reads are contiguous in j. 16 coalesced u32 stores/thread.
// NO min-occupancy bound (round-5 spill lesson).
// ---------------------------------------------------------------------------
__global__ __launch_bounds__(256) void k2_zproj(
    const float* __restrict__ z, const float* __restrict__ wb, const float* __restrict__ bb,
    const float* __restrict__ wdz, const float* __restrict__ bdz,
    float* __restrict__ BBT, uint32* __restrict__ PZT32)
{
    __shared__ float wL[CZ * 44];     // [k][44]: o<12 -> wb, else wdz
    __shared__ float biasL[44];
    const int tid = threadIdx.x;
    for (int idx = tid; idx < CZ * 44; idx += 256) {
        const int k = idx / 44, o = idx % 44;
        wL[idx] = (o < 12) ? wb[k * 12 + o] : wdz[k * 32 + (o - 12)];
    }
    if (tid < 44) biasL[tid] = (tid < 12) ? bb[tid] : bdz[tid - 12];
    __syncthreads();

    const int i = blockIdx.y;
    const int j = blockIdx.x * 256 + tid;
    const float4* zrow = (const float4*)(z + ((size_t)i * NTOK + j) * CZ);

    float acc[44];
    #pragma unroll
    for (int o = 0; o < 44; o++) acc[o] = biasL[o];

    #pragma unroll 4
    for (int k4 = 0; k4 < CZ / 4; k4++) {
        const float4 zv = zrow[k4];
        const float* w0 = &wL[(k4 * 4) * 44];
        #pragma unroll
        for (int o = 0; o < 44; o++)
            acc[o] += zv.x * w0[o] + zv.y * w0[o + 44] + zv.z * w0[o + 88] + zv.w * w0[o + 132];
    }

    #pragma unroll
    for (int h = 0; h < 12; h++) BBT[((size_t)i * 12 + h) * NTOK + j] = acc[h];

    #pragma unroll
    for (int c2 = 0; c2 < 16; c2++) {
        const uint32 pk = bf16rn(acc[12 + 2 * c2]) | (bf16rn(acc[12 + 2 * c2 + 1]) << 16);
        PZT32[((size_t)i * 16 + c2) * NTOK + j] = pk;
    }
}

// ---------------------------------------------------------------------------
// K3: attention per row i. Phase 4 is wave-cooperative (wave = head):
// lanes split j so every global load is a contiguous 1KB per wave
// (round 8: per-thread row streaming = 64 lines/instr, 285 us, ILP-null).
// ---------------------------------------------------------------------------
__global__ __launch_bounds__(768) void k3_attn(
    const float* __restrict__ KT, const float* __restrict__ VT,
    const float* __restrict__ KPT, const float* __restrict__ VPT,
    const float* __restrict__ Q, const float* __restrict__ QP,
    const float* __restrict__ BBT, const uint32* __restrict__ PZT32,
    const float* __restrict__ mask, const float* __restrict__ head_weights,
    float* __restrict__ O, float* __restrict__ OPT, float* __restrict__ OPAIR)
{
    __shared__ float LB[NH][NTOK];      // logits -> probs in place
    __shared__ float qrow[192], qprow[144], hwL[NH];
    const int i = blockIdx.x, tid = threadIdx.x;

    if (tid < 192) qrow[tid] = Q[i * 192 + tid];
    else if (tid >= 256 && tid < 400) qprow[tid - 256] = QP[i * 144 + (tid - 256)];
    else if (tid >= 448 && tid < 460)
        hwL[tid - 448] = logf(1.0f + expf(head_weights[tid - 448])) * 0.13608276348795434f; // sqrt(1/54)
    __syncthreads();

    const float qk_scale = 0.14433756729740643f;   // sqrt(1/48)
    const float b_scale  = 0.5773502691896258f;    // sqrt(1/3)
    {
        const int j = tid;
        const float mterm = INF_ * (mask[i] * mask[j] - 1.0f);
        #pragma unroll 1
        for (int h = 0; h < NH; h++) {
            float qk = 0.0f;
            #pragma unroll
            for (int c = 0; c < 16; c++)
                qk += qrow[h * 16 + c] * KT[(h * 16 + c) * NTOK + j];
            float pt = 0.0f;
            #pragma unroll
            for (int d = 0; d < 12; d++) {
                const float dv = qprow[h * 12 + d] - KPT[(h * 12 + d) * NTOK + j];
                pt += dv * dv;
            }
            LB[h][j] = qk * qk_scale + b_scale * BBT[((size_t)i * 12 + h) * NTOK + j]
                     - 0.5f * hwL[h] * pt + mterm;
        }
    }
    __syncthreads();

    const int h = tid >> 6, l = tid & 63;   // wave w = head w (12 waves exactly)

    // softmax
    {
        float m = -3.0e38f;
        for (int jj = l; jj < NTOK; jj += 64) m = fmaxf(m, LB[h][jj]);
        #pragma unroll
        for (int off = 32; off >= 1; off >>= 1) m = fmaxf(m, __shfl_xor(m, off));
        float ssum = 0.0f;
        for (int jj = l; jj < NTOK; jj += 64) {
            const float e = __expf(LB[h][jj] - m);
            LB[h][jj] = e;
            ssum += e;
        }
        #pragma unroll
        for (int off = 32; off >= 1; off >>= 1) ssum += __shfl_xor(ssum, off);
        const float inv = 1.0f / ssum;
        for (int jj = l; jj < NTOK; jj += 64) LB[h][jj] *= inv;
    }
    __syncthreads();

    // ---- phase 4: wave-cooperative weighted sums, all loads coalesced ----
    // o (16 rows of VT) + o_pt (24 rows of VPT)
    #pragma unroll 1
    for (int r = 0; r < 40; r++) {
        const float4* src = (r < 16) ? (const float4*)&VT[(h * 16 + r) * NTOK]
                                     : (const float4*)&VPT[(h * 24 + (r - 16)) * NTOK];
        const float4 v0 = src[l],       p0 = *(const float4*)&LB[h][l * 4];
        const float4 v1 = src[64 + l],  p1 = *(const float4*)&LB[h][256 + l * 4];
        const float4 v2 = src[128 + l], p2 = *(const float4*)&LB[h][512 + l * 4];
        float acc = p0.x*v0.x + p0.y*v0.y + p0.z*v0.z + p0.w*v0.w
                  + p1.x*v1.x + p1.y*v1.y + p1.z*v1.z + p1.w*v1.w
                  + p2.x*v2.x + p2.y*v2.y + p2.z*v2.z + p2.w*v2.w;
        #pragma unroll
        for (int off = 32; off >= 1; off >>= 1) acc += __shfl_xor(acc, off);
        if (l == 0) {
            if (r < 16) O[i * 192 + h * 16 + r] = acc;
            else        OPT[i * 288 + h * 24 + (r - 16)] = acc;
        }
    }
    // o_pair: 16 u32 rows of PZT32[i][c2][j]
    #pragma unroll 1
    for (int c2 = 0; c2 < 16; c2++) {
        const uint4* src = (const uint4*)&PZT32[((size_t)i * 16 + c2) * NTOK];
        float lo = 0.f, hi = 0.f;
        #pragma unroll
        for (int it = 0; it < 3; it++) {
            const uint4 u  = src[it * 64 + l];
            const float4 p = *(const float4*)&LB[h][it * 256 + l * 4];
            lo += p.x*bflo(u.x) + p.y*bflo(u.y) + p.z*bflo(u.z) + p.w*bflo(u.w);
            hi += p.x*bfhi(u.x) + p.y*bfhi(u.y) + p.z*bfhi(u.z) + p.w*bfhi(u.w);
        }
        #pragma unroll
        for (int off = 32; off >= 1; off >>= 1) {
            lo += __shfl_xor(lo, off);
            hi += __shfl_xor(hi, off);
        }
        if (l == 0) {
            OPAIR[i * 384 + h * 32 + 2 * c2]     = lo;
            OPAIR[i * 384 + h * 32 + 2 * c2 + 1] = hi;
        }
    }
}

// ---------------------------------------------------------------------------
// K4: inverse rotation + norms + concat + final linear (8 tokens/block)
// ---------------------------------------------------------------------------
#define K4T 8
__global__ __launch_bounds__(256) void k4_out(
    const float* __restrict__ O, const float* __restrict__ OPT, const float* __restrict__ OPAIR,
    const float* __restrict__ rot, const float* __restrict__ trans,
    const float* __restrict__ wout, const float* __restrict__ bout,
    float* __restrict__ out)
{
    __shared__ float f[K4T][960];
    const int n0 = blockIdx.x * K4T, tid = threadIdx.x;

    for (int idx = tid; idx < K4T * 192; idx += 256) {
        const int t = idx / 192, k = idx % 192;
        f[t][k] = O[(n0 + t) * 192 + k];
    }
    for (int idx = tid; idx < K4T * 384; idx += 256) {
        const int t = idx / 384, k = idx % 384;
        f[t][576 + k] = OPAIR[(n0 + t) * 384 + k];
    }
    for (int idx = tid; idx < K4T * 96; idx += 256) {
        const int t = idx / 96, hp = idx % 96;
        const int n = n0 + t;
        const float vx = OPT[n * 288 + hp * 3 + 0] - trans[n * 3 + 0];
        const float vy = OPT[n * 288 + hp * 3 + 1] - trans[n * 3 + 1];
        const float vz = OPT[n * 288 + hp * 3 + 2] - trans[n * 3 + 2];
        const float o0 = rot[n*9+0]*vx + rot[n*9+3]*vy + rot[n*9+6]*vz;
        const float o1 = rot[n*9+1]*vx + rot[n*9+4]*vy + rot[n*9+7]*vz;
        const float o2 = rot[n*9+2]*vx + rot[n*9+5]*vy + rot[n*9+8]*vz;
        f[t][192 + hp] = o0;
        f[t][288 + hp] = o1;
        f[t][384 + hp] = o2;
        f[t][480 + hp] = sqrtf(o0*o0 + o1*o1 + o2*o2 + EPS_);
    }
    __syncthreads();

    for (int o = tid; o < 384; o += 256) {
        float acc[K4T];
        #pragma unroll
        for (int t = 0; t < K4T; t++) acc[t] = bout[o];
        for (int k = 0; k < 960; k++) {
            const float wv = wout[k * 384 + o];
            #pragma unroll
            for (int t = 0; t < K4T; t++) acc[t] += f[t][k] * wv;
        }
        #pragma unroll
        for (int t = 0; t < K4T; t++) out[(n0 + t) * 384 + o] = acc[t];
    }
}

// ---------------------------------------------------------------------------
extern "C" void kernel_launch(void* const* d_in, const int* in_sizes, int n_in,
                              void* d_out, int out_size, void* d_ws, size_t ws_size,
                              hipStream_t stream) {
    (void)in_sizes; (void)n_in; (void)out_size; (void)ws_size;
    const float* s     = (const float*)d_in[0];
    const float* z     = (const float*)d_in[1];
    const float* rot   = (const float*)d_in[2];
    const float* trans = (const float*)d_in[3];
    const float* mask  = (const float*)d_in[4];
    const float* wq    = (const float*)d_in[5];
    const float* bq    = (const float*)d_in[6];
    const float* wkv   = (const float*)d_in[7];
    const float* bkv   = (const float*)d_in[8];
    const float* wqp   = (const float*)d_in[9];
    const float* bqp   = (const float*)d_in[10];
    const float* wkvp  = (const float*)d_in[11];
    const float* bkvp  = (const float*)d_in[12];
    const float* wb    = (const float*)d_in[13];
    const float* bb    = (const float*)d_in[14];
    const float* wdz   = (const float*)d_in[15];
    const float* bdz   = (const float*)d_in[16];
    const float* hwts  = (const float*)d_in[17];
    const float* wout  = (const float*)d_in[18];
    const float* bout  = (const float*)d_in[19];
    float* out = (float*)d_out;

    float* ws = (float*)d_ws;
    float* Q     = ws;                       // 147456
    float* KT    = Q     + 147456;           // 147456
    float* VT    = KT    + 147456;           // 147456
    float* QP    = VT    + 147456;           // 110592
    float* KPT   = QP    + 110592;           // 110592
    float* VPT   = KPT   + 110592;           // 221184
    float* O     = VPT   + 221184;           // 147456
    float* OPT   = O     + 147456;           // 221184
    float* OPAIR = OPT   + 221184;           // 294912
    float* BBT   = OPAIR + 294912;           // 7,077,888 floats (28.3 MB)
    uint32* PZT32 = (uint32*)(BBT + 7077888); // 768*16*768 u32 (37.7 MB)
    float* RAW = BBT;   // aliases BBT: dead before k2 runs

    hipLaunchKernelGGL(k1a_gemm, dim3(NTOK / 64, 1152 / 64), dim3(256), 0, stream,
                       s, wq, wkv, wqp, wkvp, RAW);
    hipLaunchKernelGGL(k1b_finish, dim3(NTOK / 16), dim3(256), 0, stream,
                       RAW, rot, trans, bq, bkv, bqp, bkvp,
                       Q, KT, VT, QP, KPT, VPT);
    hipLaunchKernelGGL(k2_zproj, dim3(3, NTOK), dim3(256), 0, stream,
                       z, wb, bb, wdz, bdz, BBT, PZT32);
    hipLaunchKernelGGL(k3_attn, dim3(NTOK), dim3(768), 0, stream,
                       KT, VT, KPT, VPT, Q, QP, BBT, PZT32, mask, hwts,
                       O, OPT, OPAIR);
    hipLaunchKernelGGL(k4_out, dim3(NTOK / K4T), dim3(256), 0, stream,
                       O, OPT, OPAIR, rot, trans, wout, bout, out);
}

// Round 10
// 445.937 us; speedup vs baseline: 1.4145x; 1.1252x over previous
//
#include <hip/hip_runtime.h>
#include <math.h>

#define NTOK 768
#define CS   384
#define CZ   128
#define NH   12
#define INF_ 100000.0f
#define EPS_ 1e-8f

typedef unsigned int  uint32;

__device__ __forceinline__ uint32 bf16rn(float x) {
    uint32 u = __float_as_uint(x);
    return (u + 0x7fffu + ((u >> 16) & 1u)) >> 16;
}
__device__ __forceinline__ float bflo(uint32 u) { return __uint_as_float((u & 0xffffu) << 16); }
__device__ __forceinline__ float bfhi(uint32 u) { return __uint_as_float(u & 0xffff0000u); }

#define QK_SCALE 0.14433756729740643f   // sqrt(1/48)
#define B_SCALE  0.5773502691896258f    // sqrt(1/3)
#define HW_SCALE 0.13608276348795434f   // sqrt(1/54)

// ---------------------------------------------------------------------------
// K1a: tiled GEMM. RAW[col][tok] = sum_k s[tok][k] * Wcat[k][col]  (no bias).
// ---------------------------------------------------------------------------
__global__ __launch_bounds__(256) void k1a_gemm(
    const float* __restrict__ s,
    const float* __restrict__ wq, const float* __restrict__ wkv,
    const float* __restrict__ wqp, const float* __restrict__ wkvp,
    float* __restrict__ RAW)
{
    __shared__ float sA[32][72];   // [k][m]
    __shared__ float sB[32][72];   // [k][n]
    const int tid  = threadIdx.x;
    const int tok0 = blockIdx.x * 64;
    const int col0 = blockIdx.y * 64;

    const int m0 = (tid & 15) * 4;
    const int n0 = (tid >> 4) * 4;

    float4 acc[4];
    #pragma unroll
    for (int nn = 0; nn < 4; nn++) acc[nn] = make_float4(0.f, 0.f, 0.f, 0.f);

    const int lam = tid >> 2, lak = (tid & 3) * 8;
    const int lbk = tid >> 3, lbc = (tid & 7) * 8;
    const int gcol = col0 + lbc;
    const float* wsrc; int wwidth, woff;
    if (gcol < 192)      { wsrc = wq;   wwidth = 192; woff = gcol; }
    else if (gcol < 576) { wsrc = wkv;  wwidth = 384; woff = gcol - 192; }
    else if (gcol < 720) { wsrc = wqp;  wwidth = 144; woff = gcol - 576; }
    else                 { wsrc = wkvp; wwidth = 432; woff = gcol - 720; }

    for (int kb = 0; kb < CS; kb += 32) {
        const float4 a0 = *(const float4*)&s[(tok0 + lam) * CS + kb + lak];
        const float4 a1 = *(const float4*)&s[(tok0 + lam) * CS + kb + lak + 4];
        const float4 b0 = *(const float4*)&wsrc[(size_t)(kb + lbk) * wwidth + woff];
        const float4 b1 = *(const float4*)&wsrc[(size_t)(kb + lbk) * wwidth + woff + 4];
        __syncthreads();
        sA[lak + 0][lam] = a0.x; sA[lak + 1][lam] = a0.y;
        sA[lak + 2][lam] = a0.z; sA[lak + 3][lam] = a0.w;
        sA[lak + 4][lam] = a1.x; sA[lak + 5][lam] = a1.y;
        sA[lak + 6][lam] = a1.z; sA[lak + 7][lam] = a1.w;
        *(float4*)&sB[lbk][lbc]     = b0;
        *(float4*)&sB[lbk][lbc + 4] = b1;
        __syncthreads();
        #pragma unroll
        for (int k = 0; k < 32; k++) {
            const float4 av = *(const float4*)&sA[k][m0];
            const float4 bv = *(const float4*)&sB[k][n0];
            acc[0].x += av.x * bv.x; acc[0].y += av.y * bv.x; acc[0].z += av.z * bv.x; acc[0].w += av.w * bv.x;
            acc[1].x += av.x * bv.y; acc[1].y += av.y * bv.y; acc[1].z += av.z * bv.y; acc[1].w += av.w * bv.y;
            acc[2].x += av.x * bv.z; acc[2].y += av.y * bv.z; acc[2].z += av.z * bv.z; acc[2].w += av.w * bv.z;
            acc[3].x += av.x * bv.w; acc[3].y += av.y * bv.w; acc[3].z += av.z * bv.w; acc[3].w += av.w * bv.w;
        }
    }
    #pragma unroll
    for (int nn = 0; nn < 4; nn++)
        *(float4*)&RAW[(size_t)(col0 + n0 + nn) * NTOK + tok0 + m0] = acc[nn];
}

// ---------------------------------------------------------------------------
// K1b: bias + rigid transform + GEMM-operand packing for the logit GEMM.
// AP[h][28][i] = [qk_scale*q (16) | hw_h*qp (12)]
// BP[h][28][j] = [k (16)          | kp (12)      ]
// RQN[h][i] = -0.5*hw*|qp|^2 ; CKN[h][j] = -0.5*hw*|kp|^2
// ---------------------------------------------------------------------------
__global__ __launch_bounds__(256) void k1b_finish(
    const float* __restrict__ RAW,
    const float* __restrict__ rot, const float* __restrict__ trans,
    const float* __restrict__ bq, const float* __restrict__ bkv,
    const float* __restrict__ bqp, const float* __restrict__ bkvp,
    const float* __restrict__ head_weights,
    float* __restrict__ VT, float* __restrict__ QP, float* __restrict__ VPT,
    float* __restrict__ AP, float* __restrict__ BP,
    float* __restrict__ RQN, float* __restrict__ CKN)
{
    __shared__ float hwS[NH];
    const int tid = threadIdx.x;
    const int t  = blockIdx.x * 16 + (tid & 15);
    const int wk = tid >> 4;                      // 16 walkers

    if (tid < NH) hwS[tid] = logf(1.0f + expf(head_weights[tid])) * HW_SCALE;

    float R[9], T3[3];
    #pragma unroll
    for (int x = 0; x < 9; x++) R[x] = rot[t * 9 + x];
    #pragma unroll
    for (int x = 0; x < 3; x++) T3[x] = trans[t * 3 + x];
    __syncthreads();

    // q -> AP (scaled)
    for (int col = wk; col < 192; col += 16) {
        const int h = col >> 4, c = col & 15;
        AP[(size_t)(h * 28 + c) * NTOK + t] = QK_SCALE * (RAW[(size_t)col * NTOK + t] + bq[col]);
    }
    // k -> BP, v -> VT
    for (int idx = wk; idx < 192; idx += 16) {
        const int h = idx >> 4, c = idx & 15;
        BP[(size_t)(h * 28 + c) * NTOK + t] = RAW[(size_t)(192 + h * 32 + c) * NTOK + t] + bkv[h * 32 + c];
        VT[idx * NTOK + t] = RAW[(size_t)(192 + h * 32 + 16 + c) * NTOK + t] + bkv[h * 32 + 16 + c];
    }
    // q points: pidx = h*4+p -> QP + AP (hw-scaled)
    for (int pidx = wk; pidx < 48; pidx += 16) {
        const int h = pidx >> 2, p = pidx & 3;
        const float r0 = RAW[(size_t)(576 + 0 * 48 + pidx) * NTOK + t] + bqp[0 * 48 + pidx];
        const float r1 = RAW[(size_t)(576 + 1 * 48 + pidx) * NTOK + t] + bqp[1 * 48 + pidx];
        const float r2 = RAW[(size_t)(576 + 2 * 48 + pidx) * NTOK + t] + bqp[2 * 48 + pidx];
        #pragma unroll
        for (int x = 0; x < 3; x++) {
            const float v = R[x*3+0]*r0 + R[x*3+1]*r1 + R[x*3+2]*r2 + T3[x];
            QP[t * 144 + pidx * 3 + x] = v;
            AP[(size_t)(h * 28 + 16 + p * 3 + x) * NTOK + t] = hwS[h] * v;
        }
    }
    // kv points: pidx = h*12+pp; pp<4 -> BP (kp), else -> VPT
    for (int pidx = wk; pidx < 144; pidx += 16) {
        const int h = pidx / 12, pp = pidx % 12;
        const float r0 = RAW[(size_t)(720 + 0 * 144 + pidx) * NTOK + t] + bkvp[0 * 144 + pidx];
        const float r1 = RAW[(size_t)(720 + 1 * 144 + pidx) * NTOK + t] + bkvp[1 * 144 + pidx];
        const float r2 = RAW[(size_t)(720 + 2 * 144 + pidx) * NTOK + t] + bkvp[2 * 144 + pidx];
        #pragma unroll
        for (int x = 0; x < 3; x++) {
            const float v = R[x*3+0]*r0 + R[x*3+1]*r1 + R[x*3+2]*r2 + T3[x];
            if (pp < 4) BP[(size_t)(h * 28 + 16 + pp * 3 + x) * NTOK + t] = v;
            else        VPT[((h * 8 + pp - 4) * 3 + x) * NTOK + t] = v;
        }
    }
    __syncthreads();
    // norms (per head, per token)
    if (wk < NH) {
        const int h = wk;
        float sq = 0.f, sk = 0.f;
        #pragma unroll
        for (int d = 0; d < 12; d++) {
            const float a = QP[t * 144 + h * 12 + d];
            sq += a * a;
            const float b = BP[(size_t)(h * 28 + 16 + d) * NTOK + t];
            sk += b * b;
        }
        RQN[h * NTOK + t] = -0.5f * hwS[h] * sq;
        CKN[h * NTOK + t] = -0.5f * hwS[h] * sk;
    }
}

// ---------------------------------------------------------------------------
// K2: z projections. BBT[i][h][j] f32; PZT32[i][c2][j] u32 (=2 bf16).
// NO min-occupancy bound (round-5 spill lesson).
// ---------------------------------------------------------------------------
__global__ __launch_bounds__(256) void k2_zproj(
    const float* __restrict__ z, const float* __restrict__ wb, const float* __restrict__ bb,
    const float* __restrict__ wdz, const float* __restrict__ bdz,
    float* __restrict__ BBT, uint32* __restrict__ PZT32)
{
    __shared__ float wL[CZ * 44];     // [k][44]: o<12 -> wb, else wdz
    __shared__ float biasL[44];
    const int tid = threadIdx.x;
    for (int idx = tid; idx < CZ * 44; idx += 256) {
        const int k = idx / 44, o = idx % 44;
        wL[idx] = (o < 12) ? wb[k * 12 + o] : wdz[k * 32 + (o - 12)];
    }
    if (tid < 44) biasL[tid] = (tid < 12) ? bb[tid] : bdz[tid - 12];
    __syncthreads();

    const int i = blockIdx.y;
    const int j = blockIdx.x * 256 + tid;
    const float4* zrow = (const float4*)(z + ((size_t)i * NTOK + j) * CZ);

    float acc[44];
    #pragma unroll
    for (int o = 0; o < 44; o++) acc[o] = biasL[o];

    #pragma unroll 4
    for (int k4 = 0; k4 < CZ / 4; k4++) {
        const float4 zv = zrow[k4];
        const float* w0 = &wL[(k4 * 4) * 44];
        #pragma unroll
        for (int o = 0; o < 44; o++)
            acc[o] += zv.x * w0[o] + zv.y * w0[o + 44] + zv.z * w0[o + 88] + zv.w * w0[o + 132];
    }

    #pragma unroll
    for (int h = 0; h < 12; h++) BBT[((size_t)i * 12 + h) * NTOK + j] = acc[h];

    #pragma unroll
    for (int c2 = 0; c2 < 16; c2++) {
        const uint32 pk = bf16rn(acc[12 + 2 * c2]) | (bf16rn(acc[12 + 2 * c2 + 1]) << 16);
        PZT32[((size_t)i * 16 + c2) * NTOK + j] = pk;
    }
}

// ---------------------------------------------------------------------------
// K3a: logit GEMM per head. LG[i][h][j] = AP_h[i].BP_h[j] + b_scale*BBT
//      + RQN[h][i] + CKN[h][j] + INF*(m_i*m_j - 1).  64x64 tiles, K=28.
// ---------------------------------------------------------------------------
__global__ __launch_bounds__(256) void k3a_logits(
    const float* __restrict__ AP, const float* __restrict__ BP,
    const float* __restrict__ RQN, const float* __restrict__ CKN,
    const float* __restrict__ BBT, const float* __restrict__ mask,
    float* __restrict__ LG)
{
    __shared__ float sA[28][64];
    __shared__ float sB[28][64];
    const int tid = threadIdx.x;
    const int j0 = blockIdx.x * 64;
    const int i0 = blockIdx.y * 64;
    const int h  = blockIdx.z;

    #pragma unroll
    for (int t = 0; t < 7; t++) {
        const int idx = tid + t * 256;
        const int row = idx >> 6, col = idx & 63;
        sA[row][col] = AP[(size_t)(h * 28 + row) * NTOK + i0 + col];
        sB[row][col] = BP[(size_t)(h * 28 + row) * NTOK + j0 + col];
    }
    __syncthreads();

    const int m0 = (tid & 15) * 4;   // i offset
    const int n0 = (tid >> 4) * 4;   // j offset

    float4 acc[4];   // acc[mm] = float4 over j
    #pragma unroll
    for (int mm = 0; mm < 4; mm++) acc[mm] = make_float4(0.f, 0.f, 0.f, 0.f);

    #pragma unroll
    for (int k = 0; k < 28; k++) {
        const float4 av = *(const float4*)&sA[k][m0];
        const float4 bv = *(const float4*)&sB[k][n0];
        acc[0].x += av.x * bv.x; acc[0].y += av.x * bv.y; acc[0].z += av.x * bv.z; acc[0].w += av.x * bv.w;
        acc[1].x += av.y * bv.x; acc[1].y += av.y * bv.y; acc[1].z += av.y * bv.z; acc[1].w += av.y * bv.w;
        acc[2].x += av.z * bv.x; acc[2].y += av.z * bv.y; acc[2].z += av.z * bv.z; acc[2].w += av.z * bv.w;
        acc[3].x += av.w * bv.x; acc[3].y += av.w * bv.y; acc[3].z += av.w * bv.z; acc[3].w += av.w * bv.w;
    }

    const float4 ck = *(const float4*)&CKN[h * NTOK + j0 + n0];
    const float4 mj = *(const float4*)&mask[j0 + n0];
    #pragma unroll
    for (int mm = 0; mm < 4; mm++) {
        const int gi = i0 + m0 + mm;
        const float rq = RQN[h * NTOK + gi];
        const float mi = mask[gi];
        const float4 bb = *(const float4*)&BBT[((size_t)gi * NH + h) * NTOK + j0 + n0];
        float4 o;
        o.x = acc[mm].x + B_SCALE * bb.x + rq + ck.x + INF_ * (mi * mj.x - 1.0f);
        o.y = acc[mm].y + B_SCALE * bb.y + rq + ck.y + INF_ * (mi * mj.y - 1.0f);
        o.z = acc[mm].z + B_SCALE * bb.z + rq + ck.z + INF_ * (mi * mj.z - 1.0f);
        o.w = acc[mm].w + B_SCALE * bb.w + rq + ck.w + INF_ * (mi * mj.w - 1.0f);
        *(float4*)&LG[((size_t)gi * NH + h) * NTOK + j0 + n0] = o;
    }
}

// ---------------------------------------------------------------------------
// K3b: per row i — load logits, softmax (wave=head), wave-cooperative sums.
// ---------------------------------------------------------------------------
__global__ __launch_bounds__(768) void k3b_attn(
    const float* __restrict__ LG,
    const float* __restrict__ VT, const float* __restrict__ VPT,
    const uint32* __restrict__ PZT32,
    float* __restrict__ O, float* __restrict__ OPT, float* __restrict__ OPAIR)
{
    __shared__ float LB[NH][NTOK];      // logits -> probs in place
    const int i = blockIdx.x, tid = threadIdx.x;

    #pragma unroll
    for (int hh = 0; hh < NH; hh++)
        LB[hh][tid] = LG[((size_t)i * NH + hh) * NTOK + tid];
    __syncthreads();

    const int h = tid >> 6, l = tid & 63;   // wave w = head w (12 waves exactly)

    // softmax
    {
        float m = -3.0e38f;
        for (int jj = l; jj < NTOK; jj += 64) m = fmaxf(m, LB[h][jj]);
        #pragma unroll
        for (int off = 32; off >= 1; off >>= 1) m = fmaxf(m, __shfl_xor(m, off));
        float ssum = 0.0f;
        for (int jj = l; jj < NTOK; jj += 64) {
            const float e = __expf(LB[h][jj] - m);
            LB[h][jj] = e;
            ssum += e;
        }
        #pragma unroll
        for (int off = 32; off >= 1; off >>= 1) ssum += __shfl_xor(ssum, off);
        const float inv = 1.0f / ssum;
        for (int jj = l; jj < NTOK; jj += 64) LB[h][jj] *= inv;
    }
    __syncthreads();

    // wave-cooperative weighted sums (all loads coalesced)
    #pragma unroll 1
    for (int r = 0; r < 40; r++) {
        const float4* src = (r < 16) ? (const float4*)&VT[(h * 16 + r) * NTOK]
                                     : (const float4*)&VPT[(h * 24 + (r - 16)) * NTOK];
        const float4 v0 = src[l],       p0 = *(const float4*)&LB[h][l * 4];
        const float4 v1 = src[64 + l],  p1 = *(const float4*)&LB[h][256 + l * 4];
        const float4 v2 = src[128 + l], p2 = *(const float4*)&LB[h][512 + l * 4];
        float acc = p0.x*v0.x + p0.y*v0.y + p0.z*v0.z + p0.w*v0.w
                  + p1.x*v1.x + p1.y*v1.y + p1.z*v1.z + p1.w*v1.w
                  + p2.x*v2.x + p2.y*v2.y + p2.z*v2.z + p2.w*v2.w;
        #pragma unroll
        for (int off = 32; off >= 1; off >>= 1) acc += __shfl_xor(acc, off);
        if (l == 0) {
            if (r < 16) O[i * 192 + h * 16 + r] = acc;
            else        OPT[i * 288 + h * 24 + (r - 16)] = acc;
        }
    }
    #pragma unroll 1
    for (int c2 = 0; c2 < 16; c2++) {
        const uint4* src = (const uint4*)&PZT32[((size_t)i * 16 + c2) * NTOK];
        float lo = 0.f, hi = 0.f;
        #pragma unroll
        for (int it = 0; it < 3; it++) {
            const uint4 u  = src[it * 64 + l];
            const float4 p = *(const float4*)&LB[h][it * 256 + l * 4];
            lo += p.x*bflo(u.x) + p.y*bflo(u.y) + p.z*bflo(u.z) + p.w*bflo(u.w);
            hi += p.x*bfhi(u.x) + p.y*bfhi(u.y) + p.z*bfhi(u.z) + p.w*bfhi(u.w);
        }
        #pragma unroll
        for (int off = 32; off >= 1; off >>= 1) {
            lo += __shfl_xor(lo, off);
            hi += __shfl_xor(hi, off);
        }
        if (l == 0) {
            OPAIR[i * 384 + h * 32 + 2 * c2]     = lo;
            OPAIR[i * 384 + h * 32 + 2 * c2 + 1] = hi;
        }
    }
}

// ---------------------------------------------------------------------------
// K4: inverse rotation + norms + concat + final linear (8 tokens/block)
// ---------------------------------------------------------------------------
#define K4T 8
__global__ __launch_bounds__(256) void k4_out(
    const float* __restrict__ O, const float* __restrict__ OPT, const float* __restrict__ OPAIR,
    const float* __restrict__ rot, const float* __restrict__ trans,
    const float* __restrict__ wout, const float* __restrict__ bout,
    float* __restrict__ out)
{
    __shared__ float f[K4T][960];
    const int n0 = blockIdx.x * K4T, tid = threadIdx.x;

    for (int idx = tid; idx < K4T * 192; idx += 256) {
        const int t = idx / 192, k = idx % 192;
        f[t][k] = O[(n0 + t) * 192 + k];
    }
    for (int idx = tid; idx < K4T * 384; idx += 256) {
        const int t = idx / 384, k = idx % 384;
        f[t][576 + k] = OPAIR[(n0 + t) * 384 + k];
    }
    for (int idx = tid; idx < K4T * 96; idx += 256) {
        const int t = idx / 96, hp = idx % 96;
        const int n = n0 + t;
        const float vx = OPT[n * 288 + hp * 3 + 0] - trans[n * 3 + 0];
        const float vy = OPT[n * 288 + hp * 3 + 1] - trans[n * 3 + 1];
        const float vz = OPT[n * 288 + hp * 3 + 2] - trans[n * 3 + 2];
        const float o0 = rot[n*9+0]*vx + rot[n*9+3]*vy + rot[n*9+6]*vz;
        const float o1 = rot[n*9+1]*vx + rot[n*9+4]*vy + rot[n*9+7]*vz;
        const float o2 = rot[n*9+2]*vx + rot[n*9+5]*vy + rot[n*9+8]*vz;
        f[t][192 + hp] = o0;
        f[t][288 + hp] = o1;
        f[t][384 + hp] = o2;
        f[t][480 + hp] = sqrtf(o0*o0 + o1*o1 + o2*o2 + EPS_);
    }
    __syncthreads();

    for (int o = tid; o < 384; o += 256) {
        float acc[K4T];
        #pragma unroll
        for (int t = 0; t < K4T; t++) acc[t] = bout[o];
        for (int k = 0; k < 960; k++) {
            const float wv = wout[k * 384 + o];
            #pragma unroll
            for (int t = 0; t < K4T; t++) acc[t] += f[t][k] * wv;
        }
        #pragma unroll
        for (int t = 0; t < K4T; t++) out[(n0 + t) * 384 + o] = acc[t];
    }
}

// ---------------------------------------------------------------------------
extern "C" void kernel_launch(void* const* d_in, const int* in_sizes, int n_in,
                              void* d_out, int out_size, void* d_ws, size_t ws_size,
                              hipStream_t stream) {
    (void)in_sizes; (void)n_in; (void)out_size; (void)ws_size;
    const float* s     = (const float*)d_in[0];
    const float* z     = (const float*)d_in[1];
    const float* rot   = (const float*)d_in[2];
    const float* trans = (const float*)d_in[3];
    const float* mask  = (const float*)d_in[4];
    const float* wq    = (const float*)d_in[5];
    const float* bq    = (const float*)d_in[6];
    const float* wkv   = (const float*)d_in[7];
    const float* bkv   = (const float*)d_in[8];
    const float* wqp   = (const float*)d_in[9];
    const float* bqp   = (const float*)d_in[10];
    const float* wkvp  = (const float*)d_in[11];
    const float* bkvp  = (const float*)d_in[12];
    const float* wb    = (const float*)d_in[13];
    const float* bb    = (const float*)d_in[14];
    const float* wdz   = (const float*)d_in[15];
    const float* bdz   = (const float*)d_in[16];
    const float* hwts  = (const float*)d_in[17];
    const float* wout  = (const float*)d_in[18];
    const float* bout  = (const float*)d_in[19];
    float* out = (float*)d_out;

    float* ws = (float*)d_ws;
    float* Q     = ws;                       // 147456 (unused, kept for layout)
    float* KT    = Q     + 147456;           // 147456 (unused)
    float* VT    = KT    + 147456;           // 147456
    float* QP    = VT    + 147456;           // 110592
    float* KPT   = QP    + 110592;           // 110592 (unused)
    float* VPT   = KPT   + 110592;           // 221184
    float* O     = VPT   + 221184;           // 147456
    float* OPT   = O     + 147456;           // 221184
    float* OPAIR = OPT   + 221184;           // 294912
    float* BBT   = OPAIR + 294912;           // 7,077,888 floats (28.3 MB)
    uint32* PZT32 = (uint32*)(BBT + 7077888); // 768*16*768 u32 (37.7 MB)
    float* AP    = BBT + 7077888 + 9437184;  // 12*28*768 = 258048
    float* BP    = AP  + 258048;             // 258048
    float* RQN   = BP  + 258048;             // 9216
    float* CKN   = RQN + 9216;               // 9216
    float* LG    = CKN + 9216;               // 7,077,888 floats (28.3 MB)
    float* RAW = BBT;   // aliases BBT: dead before k2 runs

    hipLaunchKernelGGL(k1a_gemm, dim3(NTOK / 64, 1152 / 64), dim3(256), 0, stream,
                       s, wq, wkv, wqp, wkvp, RAW);
    hipLaunchKernelGGL(k1b_finish, dim3(NTOK / 16), dim3(256), 0, stream,
                       RAW, rot, trans, bq, bkv, bqp, bkvp, hwts,
                       VT, QP, VPT, AP, BP, RQN, CKN);
    hipLaunchKernelGGL(k2_zproj, dim3(3, NTOK), dim3(256), 0, stream,
                       z, wb, bb, wdz, bdz, BBT, PZT32);
    hipLaunchKernelGGL(k3a_logits, dim3(NTOK / 64, NTOK / 64, NH), dim3(256), 0, stream,
                       AP, BP, RQN, CKN, BBT, mask, LG);
    hipLaunchKernelGGL(k3b_attn, dim3(NTOK), dim3(768), 0, stream,
                       LG, VT, VPT, PZT32, O, OPT, OPAIR);
    hipLaunchKernelGGL(k4_out, dim3(NTOK / K4T), dim3(256), 0, stream,
                       O, OPT, OPAIR, rot, trans, wout, bout, out);
}